// Round 9
// baseline (314.522 us; speedup 1.0000x reference)
//
#include <hip/hip_runtime.h>
#include <hip/hip_bf16.h>

#define N_NODES 100000
#define N_FACES 200000
#define FM 32                    // faces per tile
#define ROWS 96                  // 3 variants * FM
#define NTILES (N_FACES / FM)    // 6250
#define GRID 768
#define FS 136                   // Xff row stride (shorts)
#define ES 40                    // Xe row stride (shorts)
#define HS 136                   // H row stride (shorts)
#define W2S 136                  // W2 LDS row stride (shorts; 272B -> bank step 4, 2-way free)
#define W1K 160                  // w1t global k-stride
#define W2K 128                  // w2t global k-stride

typedef __attribute__((ext_vector_type(8))) short s8v;
typedef __attribute__((ext_vector_type(4))) short s4v;
typedef __attribute__((ext_vector_type(4))) float f4v;

static __device__ __forceinline__ short f2bf(float x) {
  __hip_bfloat16 h = __float2bfloat16(x);
  short s;
  __builtin_memcpy(&s, &h, 2);
  return s;
}
static __device__ __forceinline__ unsigned us(short x) {
  return (unsigned)(unsigned short)x;
}

// W1 -> bf16 w1t[n(128)][k(160)] with K-permutation:
//   k in [0,128): ff -> W1 row k+6 ; k in [128,134): edges -> W1 row k-128 ; else 0.
// W2 -> bf16 w2t[o(32)][k(128)].
__global__ __launch_bounds__(256) void prep_kernel(
    const float* __restrict__ W1, const float* __restrict__ W2,
    short* __restrict__ w1t, short* __restrict__ w2t)
{
  int t = blockIdx.x * 256 + threadIdx.x;
  if (t < 128 * W1K) {
    int n = t / W1K, k = t % W1K;
    float v = 0.f;
    if (k < 128) v = W1[(k + 6) * 128 + n];
    else if (k < 134) v = W1[(k - 128) * 128 + n];
    w1t[t] = f2bf(v);
  }
  if (t < 32 * W2K) {
    int o = t / W2K, k = t % W2K;
    w2t[t] = f2bf(W2[k * 32 + o]);
  }
}

// __launch_bounds__ 2nd arg empirically acts as min-BLOCKS-per-CU on this
// toolchain: (512,4)->VGPR 64, (512,6)->VGPR 40 (spill!). (512,2) -> cap 128.
__global__ __launch_bounds__(512, 2) void face_kernel(
    const float* __restrict__ pos, const float* __restrict__ ffeat,
    const float* __restrict__ b1, const float* __restrict__ b2,
    const int* __restrict__ faces,
    const short* __restrict__ w1t_g, const short* __restrict__ w2t_g,
    float* __restrict__ out_ff, float* __restrict__ sums, int* __restrict__ cnt)
{
  __shared__ short xff[FM * FS];     //  8704 B (single buffer: writes sealed by bar1/bar2)
  __shared__ short xe[ROWS * ES];    //  7680 B (single buffer: writes sealed by bar2/bar3)
  __shared__ short hbuf[ROWS * HS];  // 26112 B
  __shared__ short w2s[32 * W2S];    //  8704 B (W2T resident in LDS; frees 16 VGPR/thread)
  __shared__ int   fidx[2][ROWS];    //   768 B
  __shared__ float pvtx[ROWS * 4];   //  1536 B
  __shared__ float gsumb[FM * 30];   //  3840 B
  // total 57344 B -> 2 blocks/CU

  const int t = threadIdx.x;
  const int lane = t & 63;
  const int wv = t >> 6;             // 0..7
  const int l15 = lane & 15;
  const int lq = lane >> 4;          // 0..3
  const int kq = lq * 8;
  const int nsel = wv & 1;
  const int rt = t - 384;            // gather-lane index
  const bool rt96 = ((unsigned)rt < 96u);

  // ---- persistent W1 fragments (registers), biases
  s8v bw1[5];
#pragma unroll
  for (int kc = 0; kc < 5; ++kc)
    bw1[kc] = *(const s8v*)(w1t_g + (wv * 16 + l15) * W1K + kc * 32 + kq);
  const float b1j = b1[wv * 16 + l15];
  const float b2o = b2[nsel * 16 + l15];

  // ---- stage W2T into LDS (each thread one s8v: 512 = 32 rows x 16 chunks)
  {
    int o = t >> 4, kb = (t & 15) << 3;
    *(s8v*)&w2s[o * W2S + kb] = *(const s8v*)(w2t_g + o * W2K + kb);
  }
  // ---- zero xe pad cols 6..39 (once; never overwritten)
  if (t < ROWS) {
    s8v z = (s8v){0, 0, 0, 0, 0, 0, 0, 0};
    *(unsigned*)&xe[t * ES + 6] = 0u;
    *(s8v*)&xe[t * ES + 8] = z;
    *(s8v*)&xe[t * ES + 16] = z;
    *(s8v*)&xe[t * ES + 24] = z;
    *(s8v*)&xe[t * ES + 32] = z;
  }

  // ---- prologue: stage tile0 (ff + faces coalesced + own-vertex pos)
  int fvn = 0;  // faces value for tile i+1
  {
    int fb = blockIdx.x * FM;
    const float* fp = ffeat + ((size_t)(fb + (t >> 4)) << 7) + ((t & 15) << 3);
    f4v v0 = *(const f4v*)fp, v1 = *(const f4v*)(fp + 4);
    s8v s;
    s[0] = f2bf(v0.x); s[1] = f2bf(v0.y); s[2] = f2bf(v0.z); s[3] = f2bf(v0.w);
    s[4] = f2bf(v1.x); s[5] = f2bf(v1.y); s[6] = f2bf(v1.z); s[7] = f2bf(v1.w);
    *(s8v*)&xff[(t >> 4) * FS + ((t & 15) << 3)] = s;
    if (rt96) {
      int id = faces[fb * 3 + rt];       // coalesced
      fidx[0][rt] = id;
      pvtx[rt * 4 + 0] = pos[id * 3 + 0];
      pvtx[rt * 4 + 1] = pos[id * 3 + 1];
      pvtx[rt * 4 + 2] = pos[id * 3 + 2];
      if (blockIdx.x + GRID < NTILES)
        fvn = faces[(fb + GRID * FM) * 3 + rt];
    }
  }
  __syncthreads();
  // ---- build tile0 edges from LDS pvtx
  if (rt96) {
    int floc = rt / 3, v = rt - floc * 3;
    int rb = floc * 3 + (v == 2 ? 0 : v + 1);
    int rc = floc * 3 + (v == 0 ? 2 : v - 1);
    float ax = pvtx[rt * 4], ay = pvtx[rt * 4 + 1], az = pvtx[rt * 4 + 2];
    float bx = pvtx[rb * 4], by = pvtx[rb * 4 + 1], bz = pvtx[rb * 4 + 2];
    float cx = pvtx[rc * 4], cy = pvtx[rc * 4 + 1], cz = pvtx[rc * 4 + 2];
    int r_ = v * 32 + floc;
    s4v e;
    e[0] = f2bf(bx - ax); e[1] = f2bf(by - ay); e[2] = f2bf(bz - az); e[3] = f2bf(cx - ax);
    *(s4v*)&xe[r_ * ES] = e;
    *(unsigned*)&xe[r_ * ES + 4] = us(f2bf(cy - ay)) | (us(f2bf(cz - az)) << 16);
  }
  __syncthreads();

  int iter = 0;
  for (int tile = blockIdx.x; tile < NTILES; tile += GRID, ++iter) {
    const int cur = iter & 1, nxt = cur ^ 1;
    const int fb_c = tile * FM;
    const int tile_n = tile + GRID;
    const bool hn = tile_n < NTILES;
    const bool hn2 = tile_n + GRID < NTILES;

    // ---- top: issue ALL next-tile global loads (drain merges at bar1)
    f4v nv0, nv1;
    float npx = 0.f, npy = 0.f, npz = 0.f;
    int fvn2 = 0;
    if (hn) {
      const float* fp = ffeat + ((size_t)(tile_n * FM + (t >> 4)) << 7) + ((t & 15) << 3);
      nv0 = *(const f4v*)fp;
      nv1 = *(const f4v*)(fp + 4);
      if (rt96) {
        npx = pos[fvn * 3 + 0]; npy = pos[fvn * 3 + 1]; npz = pos[fvn * 3 + 2];
      }
    }
    if (hn2 && rt96) fvn2 = faces[(tile_n + GRID) * FM * 3 + rt];

    // ---- GEMM1: (96 x 160) @ (160 x 16-per-wave)
    f4v acc1[6];
#pragma unroll
    for (int m = 0; m < 6; ++m) acc1[m] = (f4v){0.f, 0.f, 0.f, 0.f};
#pragma unroll
    for (int kc = 0; kc < 4; ++kc) {
      s8v a0 = *(const s8v*)&xff[l15 * FS + kc * 32 + kq];
      s8v a1 = *(const s8v*)&xff[(16 + l15) * FS + kc * 32 + kq];
      acc1[0] = __builtin_amdgcn_mfma_f32_16x16x32_bf16(a0, bw1[kc], acc1[0], 0, 0, 0);
      acc1[1] = __builtin_amdgcn_mfma_f32_16x16x32_bf16(a1, bw1[kc], acc1[1], 0, 0, 0);
      acc1[2] = __builtin_amdgcn_mfma_f32_16x16x32_bf16(a0, bw1[kc], acc1[2], 0, 0, 0);
      acc1[3] = __builtin_amdgcn_mfma_f32_16x16x32_bf16(a1, bw1[kc], acc1[3], 0, 0, 0);
      acc1[4] = __builtin_amdgcn_mfma_f32_16x16x32_bf16(a0, bw1[kc], acc1[4], 0, 0, 0);
      acc1[5] = __builtin_amdgcn_mfma_f32_16x16x32_bf16(a1, bw1[kc], acc1[5], 0, 0, 0);
    }
#pragma unroll
    for (int m = 0; m < 6; ++m) {
      s8v a = *(const s8v*)&xe[(m * 16 + l15) * ES + kq];
      acc1[m] = __builtin_amdgcn_mfma_f32_16x16x32_bf16(a, bw1[4], acc1[m], 0, 0, 0);
    }

    __syncthreads();  // bar1: the ONE vmem drain point

    // ---- epi1: H write; zero gsumb; stage xff/pvtx/fidx for tile i+1
    {
      int j = wv * 16 + l15;
#pragma unroll
      for (int m = 0; m < 6; ++m)
#pragma unroll
        for (int r = 0; r < 4; ++r)
          hbuf[(m * 16 + lq * 4 + r) * HS + j] = f2bf(fmaxf(acc1[m][r] + b1j, 0.f));
    }
    for (int e = t; e < FM * 30; e += 512) gsumb[e] = 0.f;
    if (hn) {
      s8v s;
      s[0] = f2bf(nv0.x); s[1] = f2bf(nv0.y); s[2] = f2bf(nv0.z); s[3] = f2bf(nv0.w);
      s[4] = f2bf(nv1.x); s[5] = f2bf(nv1.y); s[6] = f2bf(nv1.z); s[7] = f2bf(nv1.w);
      *(s8v*)&xff[(t >> 4) * FS + ((t & 15) << 3)] = s;
      if (rt96) {
        pvtx[rt * 4 + 0] = npx; pvtx[rt * 4 + 1] = npy; pvtx[rt * 4 + 2] = npz;
        fidx[nxt][rt] = fvn;
      }
    }
    __syncthreads();  // bar2: lgkm only

    // ---- GEMM2 (c2 in regs, B from LDS) + gsumb LDS atomics + edge build (i+1)
    f4v c2a = (f4v){0.f, 0.f, 0.f, 0.f}, c2b = (f4v){0.f, 0.f, 0.f, 0.f};
    const int m0 = wv >> 1, m1 = (wv >> 1) + 4;
#pragma unroll
    for (int kk = 0; kk < 4; ++kk) {
      s8v a = *(const s8v*)&hbuf[(m0 * 16 + l15) * HS + kk * 32 + kq];
      s8v b = *(const s8v*)&w2s[(nsel * 16 + l15) * W2S + kk * 32 + kq];
      c2a = __builtin_amdgcn_mfma_f32_16x16x32_bf16(a, b, c2a, 0, 0, 0);
    }
    if (wv < 4) {
#pragma unroll
      for (int kk = 0; kk < 4; ++kk) {
        s8v a = *(const s8v*)&hbuf[(m1 * 16 + l15) * HS + kk * 32 + kq];
        s8v b = *(const s8v*)&w2s[(nsel * 16 + l15) * W2S + kk * 32 + kq];
        c2b = __builtin_amdgcn_mfma_f32_16x16x32_bf16(a, b, c2b, 0, 0, 0);
      }
    }
    const int o = nsel * 16 + l15;
    if (o >= 3) {
#pragma unroll
      for (int r = 0; r < 4; ++r)
        atomicAdd(&gsumb[((m0 * 16 + lq * 4 + r) & 31) * 30 + (o - 3)], c2a[r] + b2o);
      if (wv < 4) {
#pragma unroll
        for (int r = 0; r < 4; ++r)
          atomicAdd(&gsumb[((m1 * 16 + lq * 4 + r) & 31) * 30 + (o - 3)], c2b[r] + b2o);
      }
    }
    if (hn && rt96) {
      int floc = rt / 3, v = rt - floc * 3;
      int rb = floc * 3 + (v == 2 ? 0 : v + 1);
      int rc = floc * 3 + (v == 0 ? 2 : v - 1);
      float ax = pvtx[rt * 4], ay = pvtx[rt * 4 + 1], az = pvtx[rt * 4 + 2];
      float bx = pvtx[rb * 4], by = pvtx[rb * 4 + 1], bz = pvtx[rb * 4 + 2];
      float cx = pvtx[rc * 4], cy = pvtx[rc * 4 + 1], cz = pvtx[rc * 4 + 2];
      int r_ = v * 32 + floc;
      s4v e;
      e[0] = f2bf(bx - ax); e[1] = f2bf(by - ay); e[2] = f2bf(bz - az); e[3] = f2bf(cx - ax);
      *(s4v*)&xe[r_ * ES] = e;
      *(unsigned*)&xe[r_ * ES + 4] = us(f2bf(cy - ay)) | (us(f2bf(cz - az)) << 16);
    }
    __syncthreads();  // bar3: lgkm only

    // ---- post: out_ff write + DEFERRED global atomics (retire at next bar1)
    for (int e = t; e < FM * 29; e += 512) {
      int floc = e / 29, c = e - floc * 29;
      out_ff[((size_t)(fb_c + floc)) * 29 + c] = gsumb[floc * 30 + c] * (1.0f / 3.0f);
    }
    if (o < 3) {
#pragma unroll
      for (int r = 0; r < 4; ++r) {
        int row = m0 * 16 + lq * 4 + r;
        int nid = fidx[cur][(row & 31) * 3 + (row >> 5)];
        atomicAdd(&sums[nid * 3 + o], c2a[r] + b2o);
        if (o == 0) atomicAdd(&cnt[nid], 1);
      }
      if (wv < 4) {
#pragma unroll
        for (int r = 0; r < 4; ++r) {
          int row = m1 * 16 + lq * 4 + r;
          int nid = fidx[cur][(row & 31) * 3 + (row >> 5)];
          atomicAdd(&sums[nid * 3 + o], c2b[r] + b2o);
          if (o == 0) atomicAdd(&cnt[nid], 1);
        }
      }
    }
    fvn = fvn2;
  }
}

__global__ __launch_bounds__(256) void node_kernel(
    const float* __restrict__ pos, const float* __restrict__ sums,
    const int* __restrict__ cnt, float* __restrict__ out)
{
  int n = blockIdx.x * 256 + threadIdx.x;
  if (n >= N_NODES) return;
  float c = fmaxf((float)cnt[n], 1.0f);
#pragma unroll
  for (int o = 0; o < 3; ++o) {
    float d = sums[n * 3 + o] / c;
    out[n * 3 + o] = d;
    out[3 * N_NODES + n * 3 + o] = pos[n * 3 + o] + d;
  }
}

extern "C" void kernel_launch(void* const* d_in, const int* in_sizes, int n_in,
                              void* d_out, int out_size, void* d_ws, size_t ws_size,
                              hipStream_t stream) {
  const float* pos   = (const float*)d_in[0];
  const float* ffeat = (const float*)d_in[1];
  const float* W1    = (const float*)d_in[2];
  const float* b1    = (const float*)d_in[3];
  const float* W2    = (const float*)d_in[4];
  const float* b2    = (const float*)d_in[5];
  const int*   faces = (const int*)d_in[6];
  float* out = (float*)d_out;

  float* sums = (float*)d_ws;                  // 300000 f32
  int*   cnt  = (int*)(sums + 3 * N_NODES);    // 100000 i32
  short* w1t  = (short*)(cnt + N_NODES);       // 128*160 bf16
  short* w2t  = w1t + 128 * W1K;               // 32*128 bf16

  hipMemsetAsync(d_ws, 0, (size_t)(3 * N_NODES + N_NODES) * 4, stream);
  prep_kernel<<<80, 256, 0, stream>>>(W1, W2, w1t, w2t);
  face_kernel<<<GRID, 512, 0, stream>>>(pos, ffeat, b1, b2, faces, w1t, w2t,
                                        out + 6 * N_NODES, sums, cnt);
  node_kernel<<<(N_NODES + 255) / 256, 256, 0, stream>>>(pos, sums, cnt, out);
}

// Round 11
// 285.467 us; speedup vs baseline: 1.1018x; 1.1018x over previous
//
#include <hip/hip_runtime.h>
#include <hip/hip_bf16.h>

#define N_NODES 100000
#define N_FACES 200000
#define FM 32                    // faces per tile
#define ROWS 96                  // 3 variants * FM
#define NTILES (N_FACES / FM)    // 6250
#define GRID 512                 // == 2 blocks/CU residency; do NOT exceed
#define FS 136                   // Xff row stride (shorts)
#define ES 40                    // Xe row stride (shorts)
#define HS 136                   // H row stride (shorts)
#define W2S 136                  // W2 LDS row stride (shorts)
#define W1K 160                  // w1t global k-stride
#define W2K 128                  // w2t global k-stride

typedef __attribute__((ext_vector_type(8))) short s8v;
typedef __attribute__((ext_vector_type(4))) short s4v;
typedef __attribute__((ext_vector_type(4))) float f4v;

static __device__ __forceinline__ short f2bf(float x) {
  __hip_bfloat16 h = __float2bfloat16(x);
  short s;
  __builtin_memcpy(&s, &h, 2);
  return s;
}
static __device__ __forceinline__ unsigned us(short x) {
  return (unsigned)(unsigned short)x;
}

// W1 -> bf16 w1t[n(128)][k(160)] with K-permutation:
//   k in [0,128): ff -> W1 row k+6 ; k in [128,134): edges -> W1 row k-128 ; else 0.
// W2 -> bf16 w2t[o(32)][k(128)].
__global__ __launch_bounds__(256) void prep_kernel(
    const float* __restrict__ W1, const float* __restrict__ W2,
    short* __restrict__ w1t, short* __restrict__ w2t)
{
  int t = blockIdx.x * 256 + threadIdx.x;
  if (t < 128 * W1K) {
    int n = t / W1K, k = t % W1K;
    float v = 0.f;
    if (k < 128) v = W1[(k + 6) * 128 + n];
    else if (k < 134) v = W1[(k - 128) * 128 + n];
    w1t[t] = f2bf(v);
  }
  if (t < 32 * W2K) {
    int o = t / W2K, k = t % W2K;
    w2t[t] = f2bf(W2[k * 32 + o]);
  }
}

// __launch_bounds__ 2nd arg acts as min-BLOCKS-per-CU on this toolchain:
// (512,4)->64 VGPR, (512,6)->40 (spill), (512,2)->128 cap. Keep (512,2).
__global__ __launch_bounds__(512, 2) void face_kernel(
    const float* __restrict__ pos, const float* __restrict__ ffeat,
    const float* __restrict__ b1, const float* __restrict__ b2,
    const int* __restrict__ faces,
    const short* __restrict__ w1t_g, const short* __restrict__ w2t_g,
    float* __restrict__ out_ff, float* __restrict__ sums, int* __restrict__ cnt)
{
  // Single-buffered xff/xe: read pre-bar1 (GEMM1), written post-bar2 (GEMM2
  // phase) for tile i+1; hazards sealed by bar1/bar2 (WAR) and bar3 (RAW).
  __shared__ short xff[FM * FS];     //  8704 B
  __shared__ short xe[ROWS * ES];    //  7680 B
  __shared__ short hbuf[ROWS * HS];  // 26112 B
  __shared__ short w2s[32 * W2S];    //  8704 B
  __shared__ int   fidx[2][ROWS];    //   768 B (node id per M-row; dbuf)
  __shared__ float gsumb[FM * 30];   //  3840 B
  // total 55808 B -> 2 blocks/CU

  const int t = threadIdx.x;
  const int lane = t & 63;
  const int wv = t >> 6;             // 0..7
  const int l15 = lane & 15;
  const int lq = lane >> 4;          // 0..3
  const int kq = lq * 8;
  const int nsel = wv & 1;
  const int rt = t - 384;            // gather-lane index (rows of the tile)
  const bool rt96 = ((unsigned)rt < 96u);
  const int floc = rt & 31, vv = rt >> 5;   // M-row rt = vv*32 + floc

  // ---- persistent W1 fragments (registers), biases
  s8v bw1[5];
#pragma unroll
  for (int kc = 0; kc < 5; ++kc)
    bw1[kc] = *(const s8v*)(w1t_g + (wv * 16 + l15) * W1K + kc * 32 + kq);
  const float b1j = b1[wv * 16 + l15];
  const float b2o = b2[nsel * 16 + l15];

  // ---- stage W2T into LDS; zero xe pad cols 6..39 (once)
  {
    int o = t >> 4, kb = (t & 15) << 3;
    *(s8v*)&w2s[o * W2S + kb] = *(const s8v*)(w2t_g + o * W2K + kb);
  }
  if (t < ROWS) {
    s8v z = (s8v){0, 0, 0, 0, 0, 0, 0, 0};
    *(unsigned*)&xe[t * ES + 6] = 0u;
    *(s8v*)&xe[t * ES + 8] = z;
    *(s8v*)&xe[t * ES + 16] = z;
    *(s8v*)&xe[t * ES + 24] = z;
    *(s8v*)&xe[t * ES + 32] = z;
  }

  // ---- prologue: tile0 (ff + faces + 9 pos regs -> edges), faces(tile1)
  int ja = 0, jb = 0, jc = 0;   // my-face ids for NEXT tile (a=own vertex)
  {
    int fb = blockIdx.x * FM;
    const float* fp = ffeat + ((size_t)(fb + (t >> 4)) << 7) + ((t & 15) << 3);
    f4v v0 = *(const f4v*)fp, v1 = *(const f4v*)(fp + 4);
    s8v s;
    s[0] = f2bf(v0.x); s[1] = f2bf(v0.y); s[2] = f2bf(v0.z); s[3] = f2bf(v0.w);
    s[4] = f2bf(v1.x); s[5] = f2bf(v1.y); s[6] = f2bf(v1.z); s[7] = f2bf(v1.w);
    *(s8v*)&xff[(t >> 4) * FS + ((t & 15) << 3)] = s;
    if (rt96) {
      const int* f0 = faces + (size_t)(fb + floc) * 3;
      int i0 = f0[0], i1 = f0[1], i2 = f0[2];
      int ia = (vv == 0) ? i0 : ((vv == 1) ? i1 : i2);
      int ib = (vv == 0) ? i1 : ((vv == 1) ? i2 : i0);
      int ic = (vv == 0) ? i2 : ((vv == 1) ? i0 : i1);
      fidx[0][rt] = ia;
      float ax = pos[ia * 3], ay = pos[ia * 3 + 1], az = pos[ia * 3 + 2];
      float bx = pos[ib * 3], by = pos[ib * 3 + 1], bz = pos[ib * 3 + 2];
      float cx = pos[ic * 3], cy = pos[ic * 3 + 1], cz = pos[ic * 3 + 2];
      s4v e;
      e[0] = f2bf(bx - ax); e[1] = f2bf(by - ay); e[2] = f2bf(bz - az); e[3] = f2bf(cx - ax);
      *(s4v*)&xe[rt * ES] = e;
      *(unsigned*)&xe[rt * ES + 4] = us(f2bf(cy - ay)) | (us(f2bf(cz - az)) << 16);
      if (blockIdx.x + GRID < NTILES) {
        const int* f1 = faces + (size_t)((blockIdx.x + GRID) * FM + floc) * 3;
        int n0 = f1[0], n1 = f1[1], n2 = f1[2];
        ja = (vv == 0) ? n0 : ((vv == 1) ? n1 : n2);
        jb = (vv == 0) ? n1 : ((vv == 1) ? n2 : n0);
        jc = (vv == 0) ? n2 : ((vv == 1) ? n0 : n1);
      }
    }
  }
  __syncthreads();

  int iter = 0;
  for (int tile = blockIdx.x; tile < NTILES; tile += GRID, ++iter) {
    const int cur = iter & 1, nxt = cur ^ 1;
    const int fb_c = tile * FM;
    const int tile_n = tile + GRID;
    const bool hn = tile_n < NTILES;
    const bool hn2 = tile_n + GRID < NTILES;

    // ---- top: issue next-tile loads (consumed post-bar2 => long cover)
    f4v nv0, nv1;
    float pax = 0, pay = 0, paz = 0, pbx = 0, pby = 0, pbz = 0,
          pcx = 0, pcy = 0, pcz = 0;
    int own_n = 0, ka = 0, kb = 0, kc2 = 0;
    if (hn) {
      const float* fp = ffeat + ((size_t)(tile_n * FM + (t >> 4)) << 7) + ((t & 15) << 3);
      nv0 = *(const f4v*)fp;
      nv1 = *(const f4v*)(fp + 4);
      if (rt96) {
        own_n = ja;
        pax = pos[ja * 3]; pay = pos[ja * 3 + 1]; paz = pos[ja * 3 + 2];
        pbx = pos[jb * 3]; pby = pos[jb * 3 + 1]; pbz = pos[jb * 3 + 2];
        pcx = pos[jc * 3]; pcy = pos[jc * 3 + 1]; pcz = pos[jc * 3 + 2];
      }
    }
    if (hn2 && rt96) {
      const int* f2p = faces + (size_t)((tile_n + GRID) * FM + floc) * 3;
      int n0 = f2p[0], n1 = f2p[1], n2 = f2p[2];
      ka  = (vv == 0) ? n0 : ((vv == 1) ? n1 : n2);
      kb  = (vv == 0) ? n1 : ((vv == 1) ? n2 : n0);
      kc2 = (vv == 0) ? n2 : ((vv == 1) ? n0 : n1);
    }

    // ---- GEMM1: (96 x 160) @ (160 x 16-per-wave)
    f4v acc1[6];
#pragma unroll
    for (int m = 0; m < 6; ++m) acc1[m] = (f4v){0.f, 0.f, 0.f, 0.f};
#pragma unroll
    for (int kc = 0; kc < 4; ++kc) {
      s8v a0 = *(const s8v*)&xff[l15 * FS + kc * 32 + kq];
      s8v a1 = *(const s8v*)&xff[(16 + l15) * FS + kc * 32 + kq];
      acc1[0] = __builtin_amdgcn_mfma_f32_16x16x32_bf16(a0, bw1[kc], acc1[0], 0, 0, 0);
      acc1[1] = __builtin_amdgcn_mfma_f32_16x16x32_bf16(a1, bw1[kc], acc1[1], 0, 0, 0);
      acc1[2] = __builtin_amdgcn_mfma_f32_16x16x32_bf16(a0, bw1[kc], acc1[2], 0, 0, 0);
      acc1[3] = __builtin_amdgcn_mfma_f32_16x16x32_bf16(a1, bw1[kc], acc1[3], 0, 0, 0);
      acc1[4] = __builtin_amdgcn_mfma_f32_16x16x32_bf16(a0, bw1[kc], acc1[4], 0, 0, 0);
      acc1[5] = __builtin_amdgcn_mfma_f32_16x16x32_bf16(a1, bw1[kc], acc1[5], 0, 0, 0);
    }
#pragma unroll
    for (int m = 0; m < 6; ++m) {
      s8v a = *(const s8v*)&xe[(m * 16 + l15) * ES + kq];
      acc1[m] = __builtin_amdgcn_mfma_f32_16x16x32_bf16(a, bw1[4], acc1[m], 0, 0, 0);
    }

    __syncthreads();  // bar1

    // ---- epi1: H = relu(acc1+b1) -> hbuf; zero gsumb
    {
      int j = wv * 16 + l15;
#pragma unroll
      for (int m = 0; m < 6; ++m)
#pragma unroll
        for (int r = 0; r < 4; ++r)
          hbuf[(m * 16 + lq * 4 + r) * HS + j] = f2bf(fmaxf(acc1[m][r] + b1j, 0.f));
    }
    for (int e = t; e < FM * 30; e += 512) gsumb[e] = 0.f;
    __syncthreads();  // bar2

    // ---- GEMM2 (regs) + gsumb LDS atomics + stage tile i+1 into xff/xe/fidx
    f4v c2a = (f4v){0.f, 0.f, 0.f, 0.f}, c2b = (f4v){0.f, 0.f, 0.f, 0.f};
    const int m0 = wv >> 1, m1 = (wv >> 1) + 4;
#pragma unroll
    for (int kk = 0; kk < 4; ++kk) {
      s8v a = *(const s8v*)&hbuf[(m0 * 16 + l15) * HS + kk * 32 + kq];
      s8v b = *(const s8v*)&w2s[(nsel * 16 + l15) * W2S + kk * 32 + kq];
      c2a = __builtin_amdgcn_mfma_f32_16x16x32_bf16(a, b, c2a, 0, 0, 0);
    }
    if (wv < 4) {
#pragma unroll
      for (int kk = 0; kk < 4; ++kk) {
        s8v a = *(const s8v*)&hbuf[(m1 * 16 + l15) * HS + kk * 32 + kq];
        s8v b = *(const s8v*)&w2s[(nsel * 16 + l15) * W2S + kk * 32 + kq];
        c2b = __builtin_amdgcn_mfma_f32_16x16x32_bf16(a, b, c2b, 0, 0, 0);
      }
    }
    const int o = nsel * 16 + l15;
    if (o >= 3) {
#pragma unroll
      for (int r = 0; r < 4; ++r)
        atomicAdd(&gsumb[((m0 * 16 + lq * 4 + r) & 31) * 30 + (o - 3)], c2a[r] + b2o);
      if (wv < 4) {
#pragma unroll
        for (int r = 0; r < 4; ++r)
          atomicAdd(&gsumb[((m1 * 16 + lq * 4 + r) & 31) * 30 + (o - 3)], c2b[r] + b2o);
      }
    }
    if (hn) {
      s8v s;
      s[0] = f2bf(nv0.x); s[1] = f2bf(nv0.y); s[2] = f2bf(nv0.z); s[3] = f2bf(nv0.w);
      s[4] = f2bf(nv1.x); s[5] = f2bf(nv1.y); s[6] = f2bf(nv1.z); s[7] = f2bf(nv1.w);
      *(s8v*)&xff[(t >> 4) * FS + ((t & 15) << 3)] = s;
      if (rt96) {
        s4v e;
        e[0] = f2bf(pbx - pax); e[1] = f2bf(pby - pay);
        e[2] = f2bf(pbz - paz); e[3] = f2bf(pcx - pax);
        *(s4v*)&xe[rt * ES] = e;
        *(unsigned*)&xe[rt * ES + 4] = us(f2bf(pcy - pay)) | (us(f2bf(pcz - paz)) << 16);
        fidx[nxt][rt] = own_n;
      }
    }
    __syncthreads();  // bar3

    // ---- epi2: out_ff + deferred global atomics (drain under next GEMM1)
    for (int e = t; e < FM * 29; e += 512) {
      int fl = e / 29, c = e - fl * 29;
      out_ff[((size_t)(fb_c + fl)) * 29 + c] = gsumb[fl * 30 + c] * (1.0f / 3.0f);
    }
    if (o < 3) {
#pragma unroll
      for (int r = 0; r < 4; ++r) {
        int row = m0 * 16 + lq * 4 + r;
        int nid = fidx[cur][row];
        atomicAdd(&sums[nid * 3 + o], c2a[r] + b2o);
        if (o == 0) atomicAdd(&cnt[nid], 1);
      }
      if (wv < 4) {
#pragma unroll
        for (int r = 0; r < 4; ++r) {
          int row = m1 * 16 + lq * 4 + r;
          int nid = fidx[cur][row];
          atomicAdd(&sums[nid * 3 + o], c2b[r] + b2o);
          if (o == 0) atomicAdd(&cnt[nid], 1);
        }
      }
    }
    ja = ka; jb = kb; jc = kc2;
  }
}

__global__ __launch_bounds__(256) void node_kernel(
    const float* __restrict__ pos, const float* __restrict__ sums,
    const int* __restrict__ cnt, float* __restrict__ out)
{
  int n = blockIdx.x * 256 + threadIdx.x;
  if (n >= N_NODES) return;
  float c = fmaxf((float)cnt[n], 1.0f);
#pragma unroll
  for (int o = 0; o < 3; ++o) {
    float d = sums[n * 3 + o] / c;
    out[n * 3 + o] = d;
    out[3 * N_NODES + n * 3 + o] = pos[n * 3 + o] + d;
  }
}

extern "C" void kernel_launch(void* const* d_in, const int* in_sizes, int n_in,
                              void* d_out, int out_size, void* d_ws, size_t ws_size,
                              hipStream_t stream) {
  const float* pos   = (const float*)d_in[0];
  const float* ffeat = (const float*)d_in[1];
  const float* W1    = (const float*)d_in[2];
  const float* b1    = (const float*)d_in[3];
  const float* W2    = (const float*)d_in[4];
  const float* b2    = (const float*)d_in[5];
  const int*   faces = (const int*)d_in[6];
  float* out = (float*)d_out;

  float* sums = (float*)d_ws;                  // 300000 f32
  int*   cnt  = (int*)(sums + 3 * N_NODES);    // 100000 i32
  short* w1t  = (short*)(cnt + N_NODES);       // 128*160 bf16
  short* w2t  = w1t + 128 * W1K;               // 32*128 bf16

  hipMemsetAsync(d_ws, 0, (size_t)(3 * N_NODES + N_NODES) * 4, stream);
  prep_kernel<<<80, 256, 0, stream>>>(W1, W2, w1t, w2t);
  face_kernel<<<GRID, 512, 0, stream>>>(pos, ffeat, b1, b2, faces, w1t, w2t,
                                        out + 6 * N_NODES, sums, cnt);
  node_kernel<<<(N_NODES + 255) / 256, 256, 0, stream>>>(pos, sums, cnt, out);
}